// Round 4
// baseline (86.138 us; speedup 1.0000x reference)
//
#include <hip/hip_runtime.h>

// PS-ROI Align: img (1,20,20,1568) f32, rois (1,8192,4) f32 -> out (1,8192,7,7,32) f32
// f[b,y,x,a] = img[(y*20+x)*1568 + b*32 + a];  out[r,p,q,a], bin = p*7+q (x<-p, y<-q).
//
// Bin-major cooperative block: block = (bin, 256-ROI chunk).
//   Phase A: stage bin's full 20x20x32 slice (51.2 KB) into LDS (img is L2-resident).
//   Phase B: thread t computes the coord packet for ROI t (kills the x8 redundant
//            coordinate math of the alpha-split layout).
//   Phase C: 8 iters; 8 threads/ROI read packet (same-addr broadcast) + 9 LDS b128
//            cell reads + 36 FMA. Each 8-lane group reads a contiguous 128 B cell =
//            all 32 banks exactly once -> wave-uniform, no padding needed.

#define CH 1568
#define IMG_W 20
#define CELLS 400              // 20*20
#define IMG_F (CELLS * 32)     // 12800 floats = 51.2 KB
#define PKOFF IMG_F            // packet area: 256 rois * 8 floats = 8 KB
#define ROIS_PER_BLOCK 256

typedef float vf4 __attribute__((ext_vector_type(4)));

// Distribute the two samples' 1D bilinear weights (validity mask + reference
// clamping semantics) onto 3 consecutive cells starting at base b.
__device__ __forceinline__ void axis_weights(float s0, float s1,
                                             int& b, float& W0, float& W1, float& W2)
{
    const float f0 = floorf(s0), f1 = floorf(s1);
    const float w0 = s0 - f0,    w1 = s1 - f1;
    const float v0 = (s0 >= 0.f && s0 <= 19.f) ? 1.f : 0.f;
    const float v1 = (s1 >= 0.f && s1 <= 19.f) ? 1.f : 0.f;
    const int c00 = min(max((int)f0, 0), 19);
    const int c01 = min(c00 + 1, 19);
    const int c10 = min(max((int)f1, 0), 19);   // s1 > s0 => c10 in {c00, c00+1}
    const int c11 = min(c10 + 1, 19);
    b = c00;
    W0 = v0 * (1.f - w0);
    W1 = 0.f; W2 = 0.f;
    float t = v0 * w0;
    if (c01 == b) W0 += t; else W1 += t;
    t = v1 * (1.f - w1);
    if (c10 == b) W0 += t; else W1 += t;
    t = v1 * w1;
    const int d = c11 - b;
    W0 += (d == 0) ? t : 0.f;
    W1 += (d == 1) ? t : 0.f;
    W2 += (d == 2) ? t : 0.f;
}

__global__ __launch_bounds__(256) void psroi_kernel(
    const float* __restrict__ img,
    const float* __restrict__ rois,
    float* __restrict__ out)
{
    __shared__ float lds[IMG_F + ROIS_PER_BLOCK * 8];   // 59,392 B

    const unsigned t     = threadIdx.x;
    const unsigned bin   = blockIdx.x % 49u;
    const unsigned chunk = blockIdx.x / 49u;
    const unsigned p     = bin / 7u;          // bin_x (drives x)
    const unsigned q     = bin - p * 7u;      // bin_y (drives y)

    // ---- Phase A: stage bin slice into LDS (3200 float4, 256 threads) ----
    {
        const float* src = img + bin * 32u;
        for (unsigned idx = t; idx < CELLS * 8u; idx += 256u) {
            const unsigned cell = idx >> 3;       // 0..399
            const unsigned sub  = idx & 7u;       // float4 within cell
            const vf4 v = *(const vf4*)(src + (size_t)cell * CH + sub * 4u);
            *(vf4*)(&lds[cell * 32u + sub * 4u]) = v;
        }
    }

    // ---- Phase B: one coord packet per ROI ----
    {
        const unsigned r = chunk * ROIS_PER_BLOCK + t;
        const vf4 roi = ((const vf4*)rois)[r];
        const float step_x = roi.z * (1.0f / 7.0f);
        const float step_y = roi.w * (1.0f / 7.0f);
        const float s = 19.0f / 20.0f;
        const float sx0 = (roi.x + (float)p * step_x) * s;
        const float sx1 = (roi.x + (float)(p + 1) * step_x) * s;
        const float sy0 = (roi.y + (float)q * step_y) * s;
        const float sy1 = (roi.y + (float)(q + 1) * step_y) * s;

        int bx, by;
        float WX0, WX1, WX2, WY0, WY1, WY2;
        axis_weights(sx0, sx1, bx, WX0, WX1, WX2);
        axis_weights(sy0, sy1, by, WY0, WY1, WY2);

        vf4 p0, p1;
        p0.x = __int_as_float(bx);
        p0.y = __int_as_float(by);
        p0.z = WX0; p0.w = WX1;
        p1.x = WX2;
        p1.y = WY0 * 0.25f; p1.z = WY1 * 0.25f; p1.w = WY2 * 0.25f;  // fold mean
        *(vf4*)(&lds[PKOFF + t * 8u])     = p0;
        *(vf4*)(&lds[PKOFF + t * 8u + 4]) = p1;
    }

    __syncthreads();

    // ---- Phase C: 8 iters x (32 rois x 8 alpha-groups) ----
    const unsigned gl = t >> 3;              // group 0..31
    const unsigned a4 = (t & 7u) << 2;       // alpha offset
    const size_t out_base = ((size_t)chunk * ROIS_PER_BLOCK) * (49u * 32u) + bin * 32u + a4;

#pragma unroll
    for (unsigned k = 0; k < 8; ++k) {
        const unsigned rl = k * 32u + gl;    // roi_local 0..255
        const float* pkp = &lds[PKOFF + rl * 8u];
        const vf4 p0 = *(const vf4*)pkp;
        const vf4 p1 = *(const vf4*)(pkp + 4);
        const int bx = __float_as_int(p0.x);
        const int by = __float_as_int(p0.y);
        const float WX[3] = { p0.z, p0.w, p1.x };
        const float WY[3] = { p1.y, p1.z, p1.w };
        const int col[3] = { bx, min(bx + 1, 19), min(bx + 2, 19) };
        const int row[3] = { by, min(by + 1, 19), min(by + 2, 19) };

        vf4 acc = { 0.f, 0.f, 0.f, 0.f };
#pragma unroll
        for (int i = 0; i < 3; ++i) {
            const unsigned rowbase = (unsigned)row[i] * IMG_W;
#pragma unroll
            for (int j = 0; j < 3; ++j) {
                const vf4 v = *(const vf4*)(&lds[(rowbase + (unsigned)col[j]) * 32u + a4]);
                acc += (WY[i] * WX[j]) * v;
            }
        }
        __builtin_nontemporal_store(acc, (vf4*)(out + out_base + (size_t)rl * (49u * 32u)));
    }
}

extern "C" void kernel_launch(void* const* d_in, const int* in_sizes, int n_in,
                              void* d_out, int out_size, void* d_ws, size_t ws_size,
                              hipStream_t stream) {
    const float* img  = (const float*)d_in[0];
    const float* rois = (const float*)d_in[1];
    float* out = (float*)d_out;
    // grid = 49 bins * 32 chunks of 256 ROIs = 1568 blocks
    hipLaunchKernelGGL(psroi_kernel, dim3(1568), dim3(256), 0, stream, img, rois, out);
}

// Round 5
// 84.023 us; speedup vs baseline: 1.0252x; 1.0252x over previous
//
#include <hip/hip_runtime.h>

// PS-ROI Align: img (1,20,20,1568) f32, rois (1,8192,4) f32 -> out (1,8192,7,7,32) f32
// f[b,y,x,a] = img[(y*20+x)*1568 + b*32 + a];  out[r,p,q,a], bin = p*7+q (x<-p, y<-q).
//
// Block = (bin, 256-ROI chunk), 1024 threads.
//   Phase A: stage bin's 20x20x32 slice (51.2 KB) into LDS.
//   Phase B: threads 0..255 compute one coord packet per ROI.
//   Phase C: ONE work item per thread: (roi, alpha-group-of-8). 1 packet read,
//            9 cells x 32 B (18 ds_read_b128), ~50 FMA, 2 contiguous nt-stores.
//            4-lane groups read aligned 128 B segments -> conflict-free.

#define CH 1568
#define IMG_W 20
#define CELLS 400              // 20*20
#define IMG_F (CELLS * 32)     // 12800 floats = 51.2 KB
#define PKOFF IMG_F            // packet area: 256 rois * 8 floats = 8 KB
#define ROIS_PER_BLOCK 256

typedef float vf4 __attribute__((ext_vector_type(4)));

// Distribute the two samples' 1D bilinear weights (validity mask + reference
// clamping semantics) onto 3 consecutive cells starting at base b.
__device__ __forceinline__ void axis_weights(float s0, float s1,
                                             int& b, float& W0, float& W1, float& W2)
{
    const float f0 = floorf(s0), f1 = floorf(s1);
    const float w0 = s0 - f0,    w1 = s1 - f1;
    const float v0 = (s0 >= 0.f && s0 <= 19.f) ? 1.f : 0.f;
    const float v1 = (s1 >= 0.f && s1 <= 19.f) ? 1.f : 0.f;
    const int c00 = min(max((int)f0, 0), 19);
    const int c01 = min(c00 + 1, 19);
    const int c10 = min(max((int)f1, 0), 19);   // s1 > s0 => c10 in {c00, c00+1}
    const int c11 = min(c10 + 1, 19);
    b = c00;
    W0 = v0 * (1.f - w0);
    W1 = 0.f; W2 = 0.f;
    float t = v0 * w0;
    if (c01 == b) W0 += t; else W1 += t;
    t = v1 * (1.f - w1);
    if (c10 == b) W0 += t; else W1 += t;
    t = v1 * w1;
    const int d = c11 - b;
    W0 += (d == 0) ? t : 0.f;
    W1 += (d == 1) ? t : 0.f;
    W2 += (d == 2) ? t : 0.f;
}

__global__ __launch_bounds__(1024) void psroi_kernel(
    const float* __restrict__ img,
    const float* __restrict__ rois,
    float* __restrict__ out)
{
    __shared__ float lds[IMG_F + ROIS_PER_BLOCK * 8];   // 59,392 B

    const unsigned t     = threadIdx.x;
    const unsigned bin   = blockIdx.x % 49u;
    const unsigned chunk = blockIdx.x / 49u;
    const unsigned p     = bin / 7u;          // bin_x (drives x)
    const unsigned q     = bin - p * 7u;      // bin_y (drives y)

    // ---- Phase A: stage bin slice into LDS (3200 float4, 1024 threads) ----
    {
        const float* src = img + bin * 32u;
        for (unsigned idx = t; idx < CELLS * 8u; idx += 1024u) {
            const unsigned cell = idx >> 3;       // 0..399
            const unsigned sub  = idx & 7u;       // float4 within cell
            const vf4 v = *(const vf4*)(src + (size_t)cell * CH + sub * 4u);
            *(vf4*)(&lds[cell * 32u + sub * 4u]) = v;
        }
    }

    // ---- Phase B: threads 0..255 compute one packet per ROI ----
    if (t < ROIS_PER_BLOCK) {
        const unsigned r = chunk * ROIS_PER_BLOCK + t;
        const vf4 roi = ((const vf4*)rois)[r];
        const float step_x = roi.z * (1.0f / 7.0f);
        const float step_y = roi.w * (1.0f / 7.0f);
        const float s = 19.0f / 20.0f;
        const float sx0 = (roi.x + (float)p * step_x) * s;
        const float sx1 = (roi.x + (float)(p + 1) * step_x) * s;
        const float sy0 = (roi.y + (float)q * step_y) * s;
        const float sy1 = (roi.y + (float)(q + 1) * step_y) * s;

        int bx, by;
        float WX0, WX1, WX2, WY0, WY1, WY2;
        axis_weights(sx0, sx1, bx, WX0, WX1, WX2);
        axis_weights(sy0, sy1, by, WY0, WY1, WY2);

        vf4 p0, p1;
        p0.x = __int_as_float(bx);
        p0.y = __int_as_float(by);
        p0.z = WX0; p0.w = WX1;
        p1.x = WX2;
        p1.y = WY0 * 0.25f; p1.z = WY1 * 0.25f; p1.w = WY2 * 0.25f;  // fold mean
        *(vf4*)(&lds[PKOFF + t * 8u])     = p0;
        *(vf4*)(&lds[PKOFF + t * 8u + 4]) = p1;
    }

    __syncthreads();

    // ---- Phase C: one (roi, alpha8) work item per thread ----
    const unsigned rl = t >> 2;              // roi_local 0..255
    const unsigned a8 = (t & 3u) << 3;       // alpha float offset: 0,8,16,24

    const float* pkp = &lds[PKOFF + rl * 8u];
    const vf4 p0 = *(const vf4*)pkp;
    const vf4 p1 = *(const vf4*)(pkp + 4);
    const int bx = __float_as_int(p0.x);
    const int by = __float_as_int(p0.y);
    const float WX[3] = { p0.z, p0.w, p1.x };
    const float WY[3] = { p1.y, p1.z, p1.w };
    const int col[3] = { bx, min(bx + 1, 19), min(bx + 2, 19) };
    const int row[3] = { by, min(by + 1, 19), min(by + 2, 19) };

    vf4 acc0 = { 0.f, 0.f, 0.f, 0.f };
    vf4 acc1 = { 0.f, 0.f, 0.f, 0.f };
#pragma unroll
    for (int i = 0; i < 3; ++i) {
        const unsigned rowbase = (unsigned)row[i] * IMG_W;
#pragma unroll
        for (int j = 0; j < 3; ++j) {
            const float* cp = &lds[(rowbase + (unsigned)col[j]) * 32u + a8];
            const vf4 v0 = *(const vf4*)cp;
            const vf4 v1 = *(const vf4*)(cp + 4);
            const float wgt = WY[i] * WX[j];
            acc0 += wgt * v0;
            acc1 += wgt * v1;
        }
    }

    const size_t ob = ((size_t)chunk * ROIS_PER_BLOCK + rl) * (49u * 32u) + bin * 32u + a8;
    __builtin_nontemporal_store(acc0, (vf4*)(out + ob));
    __builtin_nontemporal_store(acc1, (vf4*)(out + ob + 4));
}

extern "C" void kernel_launch(void* const* d_in, const int* in_sizes, int n_in,
                              void* d_out, int out_size, void* d_ws, size_t ws_size,
                              hipStream_t stream) {
    const float* img  = (const float*)d_in[0];
    const float* rois = (const float*)d_in[1];
    float* out = (float*)d_out;
    // grid = 49 bins * 32 chunks of 256 ROIs = 1568 blocks of 1024 threads
    hipLaunchKernelGGL(psroi_kernel, dim3(1568), dim3(1024), 0, stream, img, rois, out);
}